// Round 5
// baseline (2911.559 us; speedup 1.0000x reference)
//
#include <hip/hip_runtime.h>

#define TSTEPS 2000
#define NBATCH 16
#define DDIM   512
#define HDIM   512
#define MTOT   (NBATCH * TSTEPS)
#define LEPS   1e-5f

typedef _Float16 f16x8 __attribute__((ext_vector_type(8)));
typedef _Float16 f16x4 __attribute__((ext_vector_type(4)));
typedef float    f32x4 __attribute__((ext_vector_type(4)));
typedef unsigned long long u64;

// ---------------- Phase 1: w = BN(x @ W^T), f16 MFMA ----------------  (r4, verified)
__global__ __launch_bounds__(256) void gemm_bn_f16_kernel(
    const float* __restrict__ x, const float* __restrict__ W,
    const float* __restrict__ gamma, const float* __restrict__ beta,
    const float* __restrict__ rmean, const float* __restrict__ rvar,
    float* __restrict__ out_a, float* __restrict__ out_z)
{
  __shared__ _Float16 Asm[128 * 64];
  __shared__ _Float16 Bsm[128 * 64];
  const int tid  = threadIdx.x;
  const int wv   = tid >> 6;
  const int lane = tid & 63;
  const int c    = lane & 15;
  const int hi   = lane >> 4;
  const int m0   = blockIdx.x * 128;
  const int n0   = blockIdx.y * 128;

  float invg[2], mng[2], btg[2];
#pragma unroll
  for (int nt = 0; nt < 2; ++nt) {
    const int gc = n0 + wv * 32 + nt * 16 + c;
    invg[nt] = gamma[gc] * rsqrtf(rvar[gc] + LEPS);
    mng[nt]  = rmean[gc];
    btg[nt]  = beta[gc];
  }

  f32x4 acc[8][2];
#pragma unroll
  for (int mt = 0; mt < 8; ++mt)
#pragma unroll
    for (int nt = 0; nt < 2; ++nt) acc[mt][nt] = (f32x4){0.f, 0.f, 0.f, 0.f};

  const int sf4  = tid & 15;
  const int srow = tid >> 4;

  for (int k0 = 0; k0 < DDIM; k0 += 64) {
    __syncthreads();
#pragma unroll
    for (int p = 0; p < 8; ++p) {
      const int r = p * 16 + srow;
      float4 va = *(const float4*)&x[(size_t)(m0 + r) * DDIM + k0 + sf4 * 4];
      float4 vb = *(const float4*)&W[(size_t)(n0 + r) * DDIM + k0 + sf4 * 4];
      f16x4 ha, hb;
      ha[0] = (_Float16)va.x; ha[1] = (_Float16)va.y;
      ha[2] = (_Float16)va.z; ha[3] = (_Float16)va.w;
      hb[0] = (_Float16)vb.x; hb[1] = (_Float16)vb.y;
      hb[2] = (_Float16)vb.z; hb[3] = (_Float16)vb.w;
      const int byo = r * 128 + ((sf4 * 8) ^ ((r & 7) << 4));
      *(f16x4*)((char*)Asm + byo) = ha;
      *(f16x4*)((char*)Bsm + byo) = hb;
    }
    __syncthreads();
#pragma unroll
    for (int kc = 0; kc < 2; ++kc) {
      const int kof = (kc * 32 + hi * 8) * 2;
      f16x8 bfr[2];
#pragma unroll
      for (int nt = 0; nt < 2; ++nt) {
        const int rr = wv * 32 + nt * 16 + c;
        bfr[nt] = *(const f16x8*)((const char*)Bsm + rr * 128 + (kof ^ ((rr & 7) << 4)));
      }
#pragma unroll
      for (int mt = 0; mt < 8; ++mt) {
        const int rr = mt * 16 + c;
        f16x8 afr = *(const f16x8*)((const char*)Asm + rr * 128 + (kof ^ ((rr & 7) << 4)));
        acc[mt][0] = __builtin_amdgcn_mfma_f32_16x16x32_f16(afr, bfr[0], acc[mt][0], 0, 0, 0);
        acc[mt][1] = __builtin_amdgcn_mfma_f32_16x16x32_f16(afr, bfr[1], acc[mt][1], 0, 0, 0);
      }
    }
  }

  const bool isA = (n0 < HDIM);
  float* dst = isA ? out_a : out_z;
  const int cb = isA ? n0 : (n0 - HDIM);
#pragma unroll
  for (int mt = 0; mt < 8; ++mt)
#pragma unroll
    for (int nt = 0; nt < 2; ++nt) {
      const int col = cb + wv * 32 + nt * 16 + c;
#pragma unroll
      for (int i = 0; i < 4; ++i) {
        const int row = m0 + mt * 16 + hi * 4 + i;
        dst[(size_t)row * HDIM + col] = (acc[mt][nt][i] - mng[nt]) * invg[nt] + btg[nt];
      }
    }
}

// ---------------- Phase 2: single-barrier in-wave a/z recurrence ----------------
// 128 blocks = 16 batches x 8 groups (bid = g*16+b). Block owns h cols
// [g0, g0+64). Wave w owns h cols j = w*8..w*8+7: its 16 B-fragment columns are
// c<8 -> a-row g0+w*8+c, c>=8 -> z-row 512+g0+w*8+(c-8). After the rank-1
// broadcast-A MFMA every lane holds gate(col c); __shfl_xor(gv,8) pairs a<->z
// IN-WAVE, so the h update + tagged publish happen right after the MFMA --
// no second barrier, no gate LDS round-trip. hbuf/hf32 parity-double-buffered
// (one barrier/step still separates buffer reuse by >=2 barriers). Ring write,
// w[t+5] prefetch, and out-store sit AFTER the publish (latency-hidden).
// Exchange: {tag,f32} packed 8-byte relaxed agent-scope atomics; equality spin
// (deadlock-free: overwrite of tag t by t+2 requires every thread to have
// passed spin(t) -- see r3 chain argument).
__global__ __launch_bounds__(512, 2) void rnn_sync_kernel(
    const float* __restrict__ U,
    float* __restrict__ out,              // [16][2000][512]: w_a in, h out (in place)
    const float* __restrict__ wz,         // [16][2000][512]
    u64* __restrict__ xbuf)               // [2][16][512] {tag,val} -- memset 0 per launch
{
  __shared__ __align__(16) _Float16 hbuf[2][512];
  __shared__ float hf32[2][512];
  __shared__ float waring[8][64];
  __shared__ float wzring[8][64];

  const int tid  = threadIdx.x;
  const int w    = tid >> 6;
  const int lane = tid & 63;
  const int c    = lane & 15;
  const int hi   = lane >> 4;
  const int bid  = blockIdx.x;
  const int b    = bid & 15, g = bid >> 4;
  const int g0   = g * 64;
  const size_t obase = (size_t)b * TSTEPS * HDIM;

  // persistent U B-fragments: in-wave a/z pairing (see header comment)
  const int urow = (c < 8) ? (g0 + w * 8 + c) : (HDIM + g0 + w * 8 + (c - 8));
  f16x8 ufrag[16];
  {
    const float* up = &U[(size_t)urow * HDIM + hi * 8];
#pragma unroll
    for (int kt = 0; kt < 16; ++kt) {
      float4 lo = *(const float4*)&up[kt * 32];
      float4 h4 = *(const float4*)&up[kt * 32 + 4];
      f16x8 f;
      f[0] = (_Float16)lo.x; f[1] = (_Float16)lo.y;
      f[2] = (_Float16)lo.z; f[3] = (_Float16)lo.w;
      f[4] = (_Float16)h4.x; f[5] = (_Float16)h4.y;
      f[6] = (_Float16)h4.z; f[7] = (_Float16)h4.w;
      ufrag[kt] = f;
    }
  }

  hbuf[0][tid] = (_Float16)0.f; hbuf[1][tid] = (_Float16)0.f;
  hf32[0][tid] = 0.f;           hf32[1][tid] = 0.f;
#pragma unroll
  for (int p = 0; p < 4; ++p) {
    if (tid < 64)        waring[p][tid]      = out[obase + (size_t)p * HDIM + g0 + tid];
    else if (tid < 128)  wzring[p][tid - 64] = wz [obase + (size_t)p * HDIM + g0 + (tid - 64)];
  }
  float pv_carry = 0.f;                      // holds w[4] entering the loop
  if (tid < 64)       pv_carry = out[obase + (size_t)4 * HDIM + g0 + tid];
  else if (tid < 128) pv_carry = wz [obase + (size_t)4 * HDIM + g0 + (tid - 64)];

  const int j    = w * 8 + (c & 7);          // this lane's h column (local)
  const bool pub = (hi == 0) && (c < 8);

  for (int t = 0; t < TSTEPS; ++t) {
    const int cur = t & 1;
    // ---- A: acquire h_t (minimum pre-barrier work) ----
    if (t > 0) {
      u64* xb = &xbuf[((size_t)cur * NBATCH + b) * HDIM];
      u64 v;
      do {
        v = __hip_atomic_load(&xb[tid], __ATOMIC_RELAXED, __HIP_MEMORY_SCOPE_AGENT);
      } while ((unsigned)(v >> 32) != (unsigned)t);
      const float hv = __uint_as_float((unsigned)v);
      hbuf[cur][tid] = (_Float16)hv;
      hf32[cur][tid] = hv;
    }
    __syncthreads();                                   // the ONLY barrier per step

    // ---- B: gates via 4 independent MFMA chains ----
    f32x4 acc0 = {0.f, 0.f, 0.f, 0.f};
    f32x4 acc1 = {0.f, 0.f, 0.f, 0.f};
    f32x4 acc2 = {0.f, 0.f, 0.f, 0.f};
    f32x4 acc3 = {0.f, 0.f, 0.f, 0.f};
#pragma unroll
    for (int ktg = 0; ktg < 4; ++ktg) {
      f16x8 af[4];
#pragma unroll
      for (int q = 0; q < 4; ++q)
        af[q] = *(const f16x8*)&hbuf[cur][ktg * 128 + q * 32 + hi * 8];
      acc0 = __builtin_amdgcn_mfma_f32_16x16x32_f16(af[0], ufrag[ktg * 4 + 0], acc0, 0, 0, 0);
      acc1 = __builtin_amdgcn_mfma_f32_16x16x32_f16(af[1], ufrag[ktg * 4 + 1], acc1, 0, 0, 0);
      acc2 = __builtin_amdgcn_mfma_f32_16x16x32_f16(af[2], ufrag[ktg * 4 + 2], acc2, 0, 0, 0);
      acc3 = __builtin_amdgcn_mfma_f32_16x16x32_f16(af[3], ufrag[ktg * 4 + 3], acc3, 0, 0, 0);
    }
    const float gv   = (acc0[0] + acc1[0]) + (acc2[0] + acc3[0]);  // gate(col c)
    const float peer = __shfl_xor(gv, 8);                          // gate(col c^8)

    // ---- C: h update (all lanes, 8x redundant) + publish (1 lane/col) ----
    const float hold = hf32[cur][g0 + j];
    const float a    = ((c < 8) ? gv : peer) + waring[t & 7][j];
    const float zg   = ((c < 8) ? peer : gv) + wzring[t & 7][j];
    const float z    = 1.f / (1.f + __expf(-zg));
    const float hc   = fmaxf(a, 0.f);
    const float hn   = z * hold + (1.f - z) * hc;
    if (pub) {
      if (t + 1 < TSTEPS) {
        const u64 pkt = ((u64)(unsigned)(t + 1) << 32) | (u64)__float_as_uint(hn);
        __hip_atomic_store(&xbuf[((size_t)((t + 1) & 1) * NBATCH + b) * HDIM + g0 + j],
                           pkt, __ATOMIC_RELAXED, __HIP_MEMORY_SCOPE_AGENT);
      }
      out[obase + (size_t)t * HDIM + g0 + j] = hn;
    }

    // ---- D: hidden tail (after publish): ring write + next prefetch ----
    if (t + 4 < TSTEPS) {
      if (tid < 64)       waring[(t + 4) & 7][tid]      = pv_carry;
      else if (tid < 128) wzring[(t + 4) & 7][tid - 64] = pv_carry;
    }
    if (t + 5 < TSTEPS) {
      if (tid < 64)       pv_carry = out[obase + (size_t)(t + 5) * HDIM + g0 + tid];
      else if (tid < 128) pv_carry = wz [obase + (size_t)(t + 5) * HDIM + g0 + (tid - 64)];
    }
  }
}

extern "C" void kernel_launch(void* const* d_in, const int* in_sizes, int n_in,
                              void* d_out, int out_size, void* d_ws, size_t ws_size,
                              hipStream_t stream) {
  const float* x     = (const float*)d_in[0];
  const float* W     = (const float*)d_in[1];
  const float* U     = (const float*)d_in[2];
  const float* gamma = (const float*)d_in[3];
  const float* beta  = (const float*)d_in[4];
  const float* rmean = (const float*)d_in[5];
  const float* rvar  = (const float*)d_in[6];
  float* out = (float*)d_out;

  const size_t wz_bytes = (size_t)MTOT * HDIM * sizeof(float);   // 65,536,000
  float* wzp = (float*)d_ws;
  u64*  xbuf = (u64*)((char*)d_ws + wz_bytes);                   // [2][16][512] u64

  hipMemsetAsync(xbuf, 0, (size_t)2 * NBATCH * HDIM * sizeof(u64), stream);

  dim3 g1(MTOT / 128, (HDIM * 2) / 128), b1(256);
  gemm_bn_f16_kernel<<<g1, b1, 0, stream>>>(x, W, gamma, beta, rmean, rvar, out, wzp);
  rnn_sync_kernel<<<dim3(128), dim3(512), 0, stream>>>(U, out, wzp, xbuf);
}

// Round 6
// 2665.955 us; speedup vs baseline: 1.0921x; 1.0921x over previous
//
#include <hip/hip_runtime.h>

#define TSTEPS 2000
#define NBATCH 16
#define DDIM   512
#define HDIM   512
#define MTOT   (NBATCH * TSTEPS)
#define LEPS   1e-5f

typedef _Float16 f16x8 __attribute__((ext_vector_type(8)));
typedef _Float16 f16x4 __attribute__((ext_vector_type(4)));
typedef float    f32x4 __attribute__((ext_vector_type(4)));
typedef unsigned long long u64;

// ---------------- Phase 1: w = BN(x @ W^T), f16 MFMA ----------------  (r4, verified ~70us)
__global__ __launch_bounds__(256) void gemm_bn_f16_kernel(
    const float* __restrict__ x, const float* __restrict__ W,
    const float* __restrict__ gamma, const float* __restrict__ beta,
    const float* __restrict__ rmean, const float* __restrict__ rvar,
    float* __restrict__ out_a, float* __restrict__ out_z)
{
  __shared__ _Float16 Asm[128 * 64];
  __shared__ _Float16 Bsm[128 * 64];
  const int tid  = threadIdx.x;
  const int wv   = tid >> 6;
  const int lane = tid & 63;
  const int c    = lane & 15;
  const int hi   = lane >> 4;
  const int m0   = blockIdx.x * 128;
  const int n0   = blockIdx.y * 128;

  float invg[2], mng[2], btg[2];
#pragma unroll
  for (int nt = 0; nt < 2; ++nt) {
    const int gc = n0 + wv * 32 + nt * 16 + c;
    invg[nt] = gamma[gc] * rsqrtf(rvar[gc] + LEPS);
    mng[nt]  = rmean[gc];
    btg[nt]  = beta[gc];
  }

  f32x4 acc[8][2];
#pragma unroll
  for (int mt = 0; mt < 8; ++mt)
#pragma unroll
    for (int nt = 0; nt < 2; ++nt) acc[mt][nt] = (f32x4){0.f, 0.f, 0.f, 0.f};

  const int sf4  = tid & 15;
  const int srow = tid >> 4;

  for (int k0 = 0; k0 < DDIM; k0 += 64) {
    __syncthreads();
#pragma unroll
    for (int p = 0; p < 8; ++p) {
      const int r = p * 16 + srow;
      float4 va = *(const float4*)&x[(size_t)(m0 + r) * DDIM + k0 + sf4 * 4];
      float4 vb = *(const float4*)&W[(size_t)(n0 + r) * DDIM + k0 + sf4 * 4];
      f16x4 ha, hb;
      ha[0] = (_Float16)va.x; ha[1] = (_Float16)va.y;
      ha[2] = (_Float16)va.z; ha[3] = (_Float16)va.w;
      hb[0] = (_Float16)vb.x; hb[1] = (_Float16)vb.y;
      hb[2] = (_Float16)vb.z; hb[3] = (_Float16)vb.w;
      const int byo = r * 128 + ((sf4 * 8) ^ ((r & 7) << 4));
      *(f16x4*)((char*)Asm + byo) = ha;
      *(f16x4*)((char*)Bsm + byo) = hb;
    }
    __syncthreads();
#pragma unroll
    for (int kc = 0; kc < 2; ++kc) {
      const int kof = (kc * 32 + hi * 8) * 2;
      f16x8 bfr[2];
#pragma unroll
      for (int nt = 0; nt < 2; ++nt) {
        const int rr = wv * 32 + nt * 16 + c;
        bfr[nt] = *(const f16x8*)((const char*)Bsm + rr * 128 + (kof ^ ((rr & 7) << 4)));
      }
#pragma unroll
      for (int mt = 0; mt < 8; ++mt) {
        const int rr = mt * 16 + c;
        f16x8 afr = *(const f16x8*)((const char*)Asm + rr * 128 + (kof ^ ((rr & 7) << 4)));
        acc[mt][0] = __builtin_amdgcn_mfma_f32_16x16x32_f16(afr, bfr[0], acc[mt][0], 0, 0, 0);
        acc[mt][1] = __builtin_amdgcn_mfma_f32_16x16x32_f16(afr, bfr[1], acc[mt][1], 0, 0, 0);
      }
    }
  }

  const bool isA = (n0 < HDIM);
  float* dst = isA ? out_a : out_z;
  const int cb = isA ? n0 : (n0 - HDIM);
#pragma unroll
  for (int mt = 0; mt < 8; ++mt)
#pragma unroll
    for (int nt = 0; nt < 2; ++nt) {
      const int col = cb + wv * 32 + nt * 16 + c;
#pragma unroll
      for (int i = 0; i < 4; ++i) {
        const int row = m0 + mt * 16 + hi * 4 + i;
        dst[(size_t)row * HDIM + col] = (acc[mt][nt][i] - mng[nt]) * invg[nt] + btg[nt];
      }
    }
}

// ---------------- Phase 2: r3 skeleton, micro-tuned ----------------
// 128 blocks = 16 batches x 8 groups (bid = g*16+b). Block owns h cols
// [g0,g0+64): U rows g0..+64 (a) and 512+g0..+64 (z) as f16 B-fragments
// (wave w owns local gate cols [w*16,w*16+16)). Per step:
//   A: each thread equality-spins on its {tag,h} atom, cvt->hbuf (f16);
//      issue w[t+5] prefetch (no wait); bar1.
//   B: rank-1 broadcast-A MFMA, 4 independent chains; 16 lanes/wave -> gbuf; bar2.
//   C: threads 0..63: gate math (hold carried in REGISTER from t-1 -- own
//      column's h_t is our own previous hn), publish {t+1,hn} FIRST (one
//      coalesced 64-lane store), then out-store, then ring-write slot t+4
//      from pv_carry (loaded a full iteration ago -> vmcnt free, post-publish).
// Deadlock/race safety: identical to r3 (passed r3/r4/r5) -- publish(t+1)
// is data+control dependent on spin(t) loads; all blocks' tag-(t-1) reads
// complete before any tag-t publish, so slot overwrite never races a reader.
__global__ __launch_bounds__(512, 2) void rnn_sync_kernel(
    const float* __restrict__ U,
    float* __restrict__ out,              // [16][2000][512]: w_a in, h out (in place)
    const float* __restrict__ wz,         // [16][2000][512]
    u64* __restrict__ xbuf)               // [2][16][512] {tag,val} -- memset 0 per launch
{
  __shared__ __align__(16) _Float16 hbuf[512];
  __shared__ float gbuf[128];
  __shared__ float waring[8][64];
  __shared__ float wzring[8][64];

  const int tid  = threadIdx.x;
  const int w    = tid >> 6;
  const int lane = tid & 63;
  const int c    = lane & 15;
  const int hi   = lane >> 4;
  const int bid  = blockIdx.x;
  const int b    = bid & 15, g = bid >> 4;
  const int g0   = g * 64;
  const size_t obase = (size_t)b * TSTEPS * HDIM;

  // persistent U B-fragments: wave w owns local gate cols [w*16, w*16+16)
  const int L    = w * 16 + c;
  const int urow = (L < 64) ? (g0 + L) : (HDIM + g0 + (L - 64));
  f16x8 ufrag[16];
  {
    const float* up = &U[(size_t)urow * HDIM + hi * 8];
#pragma unroll
    for (int kt = 0; kt < 16; ++kt) {
      float4 lo = *(const float4*)&up[kt * 32];
      float4 h4 = *(const float4*)&up[kt * 32 + 4];
      f16x8 f;
      f[0] = (_Float16)lo.x; f[1] = (_Float16)lo.y;
      f[2] = (_Float16)lo.z; f[3] = (_Float16)lo.w;
      f[4] = (_Float16)h4.x; f[5] = (_Float16)h4.y;
      f[6] = (_Float16)h4.z; f[7] = (_Float16)h4.w;
      ufrag[kt] = f;
    }
  }

  hbuf[tid] = (_Float16)0.f;
#pragma unroll
  for (int p = 0; p < 4; ++p) {
    if (tid < 64)        waring[p][tid]      = out[obase + (size_t)p * HDIM + g0 + tid];
    else if (tid < 128)  wzring[p][tid - 64] = wz [obase + (size_t)p * HDIM + g0 + (tid - 64)];
  }
  float pv_carry = 0.f;                      // holds w[t+4] entering iteration t
  if (tid < 64)       pv_carry = out[obase + (size_t)4 * HDIM + g0 + tid];
  else if (tid < 128) pv_carry = wz [obase + (size_t)4 * HDIM + g0 + (tid - 64)];
  float hold = 0.f;                          // h_t[own col], register-carried (h0 = 0)
  __syncthreads();

  for (int t = 0; t < TSTEPS; ++t) {
    // ---- A: acquire h_t (minimum pre-barrier work) ----
    if (t > 0) {
      u64* xb = &xbuf[((size_t)(t & 1) * NBATCH + b) * HDIM];
      u64 v;
      do {
        v = __hip_atomic_load(&xb[tid], __ATOMIC_RELAXED, __HIP_MEMORY_SCOPE_AGENT);
      } while ((unsigned)(v >> 32) != (unsigned)t);
      hbuf[tid] = (_Float16)__uint_as_float((unsigned)v);
    }
    // issue w[t+5] prefetch (no wait here; consumed next iteration post-publish)
    float pv_next = 0.f;
    if (t + 5 < TSTEPS) {
      if (tid < 64)       pv_next = out[obase + (size_t)(t + 5) * HDIM + g0 + tid];
      else if (tid < 128) pv_next = wz [obase + (size_t)(t + 5) * HDIM + g0 + (tid - 64)];
    }
    __syncthreads();                                   // bar1: hbuf ready

    // ---- B: gates, 4 independent MFMA chains (depth 4) ----
    f32x4 acc0 = {0.f, 0.f, 0.f, 0.f};
    f32x4 acc1 = {0.f, 0.f, 0.f, 0.f};
    f32x4 acc2 = {0.f, 0.f, 0.f, 0.f};
    f32x4 acc3 = {0.f, 0.f, 0.f, 0.f};
#pragma unroll
    for (int ktg = 0; ktg < 4; ++ktg) {
      f16x8 af[4];
#pragma unroll
      for (int q = 0; q < 4; ++q)
        af[q] = *(const f16x8*)&hbuf[ktg * 128 + q * 32 + hi * 8];
      acc0 = __builtin_amdgcn_mfma_f32_16x16x32_f16(af[0], ufrag[ktg * 4 + 0], acc0, 0, 0, 0);
      acc1 = __builtin_amdgcn_mfma_f32_16x16x32_f16(af[1], ufrag[ktg * 4 + 1], acc1, 0, 0, 0);
      acc2 = __builtin_amdgcn_mfma_f32_16x16x32_f16(af[2], ufrag[ktg * 4 + 2], acc2, 0, 0, 0);
      acc3 = __builtin_amdgcn_mfma_f32_16x16x32_f16(af[3], ufrag[ktg * 4 + 3], acc3, 0, 0, 0);
    }
    if (lane < 16) gbuf[w * 16 + lane] = (acc0[0] + acc1[0]) + (acc2[0] + acc3[0]);
    __syncthreads();                                   // bar2: gbuf ready

    // ---- C: h update + publish (threads 0..63), then hidden tail ----
    if (tid < 64) {
      const float a  = gbuf[tid]      + waring[t & 7][tid];
      const float zg = gbuf[64 + tid] + wzring[t & 7][tid];
      const float z  = 1.f / (1.f + __expf(-zg));
      const float hc = fmaxf(a, 0.f);
      const float hn = z * hold + (1.f - z) * hc;
      hold = hn;                                       // becomes h_{t+1}[own col]
      if (t + 1 < TSTEPS) {                            // publish FIRST (critical path)
        const u64 pkt = ((u64)(unsigned)(t + 1) << 32) | (u64)__float_as_uint(hn);
        __hip_atomic_store(&xbuf[((size_t)((t + 1) & 1) * NBATCH + b) * HDIM + g0 + tid],
                           pkt, __ATOMIC_RELAXED, __HIP_MEMORY_SCOPE_AGENT);
      }
      out[obase + (size_t)t * HDIM + g0 + tid] = hn;   // off critical path
    }
    // ring write slot t+4 (pv_carry issued a full iteration ago -> free wait)
    if (t + 4 < TSTEPS) {
      if (tid < 64)       waring[(t + 4) & 7][tid]      = pv_carry;
      else if (tid < 128) wzring[(t + 4) & 7][tid - 64] = pv_carry;
    }
    pv_carry = pv_next;
  }
}

extern "C" void kernel_launch(void* const* d_in, const int* in_sizes, int n_in,
                              void* d_out, int out_size, void* d_ws, size_t ws_size,
                              hipStream_t stream) {
  const float* x     = (const float*)d_in[0];
  const float* W     = (const float*)d_in[1];
  const float* U     = (const float*)d_in[2];
  const float* gamma = (const float*)d_in[3];
  const float* beta  = (const float*)d_in[4];
  const float* rmean = (const float*)d_in[5];
  const float* rvar  = (const float*)d_in[6];
  float* out = (float*)d_out;

  const size_t wz_bytes = (size_t)MTOT * HDIM * sizeof(float);   // 65,536,000
  float* wzp = (float*)d_ws;
  u64*  xbuf = (u64*)((char*)d_ws + wz_bytes);                   // [2][16][512] u64

  hipMemsetAsync(xbuf, 0, (size_t)2 * NBATCH * HDIM * sizeof(u64), stream);

  dim3 g1(MTOT / 128, (HDIM * 2) / 128), b1(256);
  gemm_bn_f16_kernel<<<g1, b1, 0, stream>>>(x, W, gamma, beta, rmean, rvar, out, wzp);
  rnn_sync_kernel<<<dim3(128), dim3(512), 0, stream>>>(U, out, wzp, xbuf);
}

// Round 7
// 2657.277 us; speedup vs baseline: 1.0957x; 1.0033x over previous
//
#include <hip/hip_runtime.h>

#define TSTEPS 2000
#define NBATCH 16
#define DDIM   512
#define HDIM   512
#define MTOT   (NBATCH * TSTEPS)
#define LEPS   1e-5f

typedef _Float16 f16x8 __attribute__((ext_vector_type(8)));
typedef _Float16 f16x4 __attribute__((ext_vector_type(4)));
typedef float    f32x4 __attribute__((ext_vector_type(4)));
typedef unsigned long long u64;

// ---------------- Phase 1: w = BN(x @ W^T), f16 MFMA ----------------  (r4, verified ~70us)
__global__ __launch_bounds__(256) void gemm_bn_f16_kernel(
    const float* __restrict__ x, const float* __restrict__ W,
    const float* __restrict__ gamma, const float* __restrict__ beta,
    const float* __restrict__ rmean, const float* __restrict__ rvar,
    float* __restrict__ out_a, float* __restrict__ out_z)
{
  __shared__ _Float16 Asm[128 * 64];
  __shared__ _Float16 Bsm[128 * 64];
  const int tid  = threadIdx.x;
  const int wv   = tid >> 6;
  const int lane = tid & 63;
  const int c    = lane & 15;
  const int hi   = lane >> 4;
  const int m0   = blockIdx.x * 128;
  const int n0   = blockIdx.y * 128;

  float invg[2], mng[2], btg[2];
#pragma unroll
  for (int nt = 0; nt < 2; ++nt) {
    const int gc = n0 + wv * 32 + nt * 16 + c;
    invg[nt] = gamma[gc] * rsqrtf(rvar[gc] + LEPS);
    mng[nt]  = rmean[gc];
    btg[nt]  = beta[gc];
  }

  f32x4 acc[8][2];
#pragma unroll
  for (int mt = 0; mt < 8; ++mt)
#pragma unroll
    for (int nt = 0; nt < 2; ++nt) acc[mt][nt] = (f32x4){0.f, 0.f, 0.f, 0.f};

  const int sf4  = tid & 15;
  const int srow = tid >> 4;

  for (int k0 = 0; k0 < DDIM; k0 += 64) {
    __syncthreads();
#pragma unroll
    for (int p = 0; p < 8; ++p) {
      const int r = p * 16 + srow;
      float4 va = *(const float4*)&x[(size_t)(m0 + r) * DDIM + k0 + sf4 * 4];
      float4 vb = *(const float4*)&W[(size_t)(n0 + r) * DDIM + k0 + sf4 * 4];
      f16x4 ha, hb;
      ha[0] = (_Float16)va.x; ha[1] = (_Float16)va.y;
      ha[2] = (_Float16)va.z; ha[3] = (_Float16)va.w;
      hb[0] = (_Float16)vb.x; hb[1] = (_Float16)vb.y;
      hb[2] = (_Float16)vb.z; hb[3] = (_Float16)vb.w;
      const int byo = r * 128 + ((sf4 * 8) ^ ((r & 7) << 4));
      *(f16x4*)((char*)Asm + byo) = ha;
      *(f16x4*)((char*)Bsm + byo) = hb;
    }
    __syncthreads();
#pragma unroll
    for (int kc = 0; kc < 2; ++kc) {
      const int kof = (kc * 32 + hi * 8) * 2;
      f16x8 bfr[2];
#pragma unroll
      for (int nt = 0; nt < 2; ++nt) {
        const int rr = wv * 32 + nt * 16 + c;
        bfr[nt] = *(const f16x8*)((const char*)Bsm + rr * 128 + (kof ^ ((rr & 7) << 4)));
      }
#pragma unroll
      for (int mt = 0; mt < 8; ++mt) {
        const int rr = mt * 16 + c;
        f16x8 afr = *(const f16x8*)((const char*)Asm + rr * 128 + (kof ^ ((rr & 7) << 4)));
        acc[mt][0] = __builtin_amdgcn_mfma_f32_16x16x32_f16(afr, bfr[0], acc[mt][0], 0, 0, 0);
        acc[mt][1] = __builtin_amdgcn_mfma_f32_16x16x32_f16(afr, bfr[1], acc[mt][1], 0, 0, 0);
      }
    }
  }

  const bool isA = (n0 < HDIM);
  float* dst = isA ? out_a : out_z;
  const int cb = isA ? n0 : (n0 - HDIM);
#pragma unroll
  for (int mt = 0; mt < 8; ++mt)
#pragma unroll
    for (int nt = 0; nt < 2; ++nt) {
      const int col = cb + wv * 32 + nt * 16 + c;
#pragma unroll
      for (int i = 0; i < 4; ++i) {
        const int row = m0 + mt * 16 + hi * 4 + i;
        dst[(size_t)row * HDIM + col] = (acc[mt][nt][i] - mng[nt]) * invg[nt] + btg[nt];
      }
    }
}

// ---------------- Phase 2: EXACT r3 structure + tail-issued prefetch ----------------
// r3 (2445us champion) byte-level skeleton: hf32 LDS hold, 2x depth-8 MFMA
// chains, expf, out-store THEN publish, gbuf + two barriers. ONE mechanism
// change: the w-prefetch global load is ISSUED in the post-publish tail and
// carried one full iteration in a register (ring depth 8). Pre-bar1 region is
// now spin + ds_writes only -- bar1's implicit s_waitcnt vmcnt(0) no longer
// drains a just-issued L3/HBM load on the critical path (it drains a load
// issued ~1 full step earlier, long complete).
// Ring safety: tail of iter t writes slot (t+3)&7 (read at iter t+3, barrier-
// ordered); slots touched by readers at t..t+2 are distinct mod 8.
__global__ __launch_bounds__(512, 2) void rnn_sync_kernel(
    const float* __restrict__ U,
    float* __restrict__ out,              // [16][2000][512]: w_a in, h out (in place)
    const float* __restrict__ wz,         // [16][2000][512]
    u64* __restrict__ xbuf)               // [2][16][512] {tag,val} -- memset 0 per launch
{
  __shared__ __align__(16) _Float16 hbuf[512];
  __shared__ float hf32[512];
  __shared__ float gbuf[128];
  __shared__ float waring[8][64];
  __shared__ float wzring[8][64];

  const int tid  = threadIdx.x;
  const int w    = tid >> 6;
  const int lane = tid & 63;
  const int c    = lane & 15;
  const int hi   = lane >> 4;
  const int bid  = blockIdx.x;
  const int b    = bid & 15, g = bid >> 4;
  const int g0   = g * 64;
  const size_t obase = (size_t)b * TSTEPS * HDIM;

  // persistent U B-fragments: wave w owns local gate cols [w*16, w*16+16)
  const int L    = w * 16 + c;
  const int urow = (L < 64) ? (g0 + L) : (HDIM + g0 + (L - 64));
  f16x8 ufrag[16];
  {
    const float* up = &U[(size_t)urow * HDIM + hi * 8];
#pragma unroll
    for (int kt = 0; kt < 16; ++kt) {
      float4 lo = *(const float4*)&up[kt * 32];
      float4 h4 = *(const float4*)&up[kt * 32 + 4];
      f16x8 f;
      f[0] = (_Float16)lo.x; f[1] = (_Float16)lo.y;
      f[2] = (_Float16)lo.z; f[3] = (_Float16)lo.w;
      f[4] = (_Float16)h4.x; f[5] = (_Float16)h4.y;
      f[6] = (_Float16)h4.z; f[7] = (_Float16)h4.w;
      ufrag[kt] = f;
    }
  }

  hbuf[tid] = (_Float16)0.f;
  hf32[tid] = 0.f;
#pragma unroll
  for (int p = 0; p < 3; ++p) {
    if (tid < 64)        waring[p][tid]      = out[obase + (size_t)p * HDIM + g0 + tid];
    else if (tid < 128)  wzring[p][tid - 64] = wz [obase + (size_t)p * HDIM + g0 + (tid - 64)];
  }
  float pv_carry = 0.f;                      // holds w[t+3] entering iteration t
  if (tid < 64)       pv_carry = out[obase + (size_t)3 * HDIM + g0 + tid];
  else if (tid < 128) pv_carry = wz [obase + (size_t)3 * HDIM + g0 + (tid - 64)];
  __syncthreads();

  for (int t = 0; t < TSTEPS; ++t) {
    // ---- A: acquire h_t -- spin + LDS write ONLY before bar1 ----
    if (t > 0) {
      u64* xb = &xbuf[((size_t)(t & 1) * NBATCH + b) * HDIM];
      u64 v;
      do {
        v = __hip_atomic_load(&xb[tid], __ATOMIC_RELAXED, __HIP_MEMORY_SCOPE_AGENT);
      } while ((unsigned)(v >> 32) != (unsigned)t);
      const float hv = __uint_as_float((unsigned)v);
      hbuf[tid] = (_Float16)hv;
      hf32[tid] = hv;
    }
    __syncthreads();                                   // bar1: hbuf/hf32 ready

    const float hold = (tid < 64) ? hf32[g0 + tid] : 0.f;  // read before bar2

    // ---- B: gates (r3's 2 interleaved MFMA chains) ----
    f32x4 acc0 = {0.f, 0.f, 0.f, 0.f};
    f32x4 acc1 = {0.f, 0.f, 0.f, 0.f};
#pragma unroll
    for (int ktg = 0; ktg < 4; ++ktg) {
      f16x8 af[4];
#pragma unroll
      for (int q = 0; q < 4; ++q)
        af[q] = *(const f16x8*)&hbuf[ktg * 128 + q * 32 + hi * 8];
      acc0 = __builtin_amdgcn_mfma_f32_16x16x32_f16(af[0], ufrag[ktg * 4 + 0], acc0, 0, 0, 0);
      acc1 = __builtin_amdgcn_mfma_f32_16x16x32_f16(af[1], ufrag[ktg * 4 + 1], acc1, 0, 0, 0);
      acc0 = __builtin_amdgcn_mfma_f32_16x16x32_f16(af[2], ufrag[ktg * 4 + 2], acc0, 0, 0, 0);
      acc1 = __builtin_amdgcn_mfma_f32_16x16x32_f16(af[3], ufrag[ktg * 4 + 3], acc1, 0, 0, 0);
    }
    if (lane < 16) gbuf[w * 16 + lane] = acc0[0] + acc1[0];
    __syncthreads();                                   // bar2: gbuf ready

    // ---- C: h update + publish (r3 order: out store, then publish) ----
    if (tid < 64) {
      const float a  = gbuf[tid]      + waring[t & 7][tid];
      const float zg = gbuf[64 + tid] + wzring[t & 7][tid];
      const float z  = 1.f / (1.f + expf(-zg));
      const float hc = fmaxf(a, 0.f);
      const float hn = z * hold + (1.f - z) * hc;
      out[obase + (size_t)t * HDIM + g0 + tid] = hn;
      if (t + 1 < TSTEPS) {
        const u64 pkt = ((u64)(unsigned)(t + 1) << 32) | (u64)__float_as_uint(hn);
        __hip_atomic_store(&xbuf[((size_t)((t + 1) & 1) * NBATCH + b) * HDIM + g0 + tid],
                           pkt, __ATOMIC_RELAXED, __HIP_MEMORY_SCOPE_AGENT);
      }
    }

    // ---- D: hidden tail -- ring write (carry from last iter) + NEW issue ----
    if (t + 3 < TSTEPS) {
      if (tid < 64)       waring[(t + 3) & 7][tid]      = pv_carry;
      else if (tid < 128) wzring[(t + 3) & 7][tid - 64] = pv_carry;
    }
    if (t + 4 < TSTEPS) {   // issue w[t+4]; vmcnt-waited a full iteration later
      if (tid < 64)       pv_carry = out[obase + (size_t)(t + 4) * HDIM + g0 + tid];
      else if (tid < 128) pv_carry = wz [obase + (size_t)(t + 4) * HDIM + g0 + (tid - 64)];
    }
  }
}

extern "C" void kernel_launch(void* const* d_in, const int* in_sizes, int n_in,
                              void* d_out, int out_size, void* d_ws, size_t ws_size,
                              hipStream_t stream) {
  const float* x     = (const float*)d_in[0];
  const float* W     = (const float*)d_in[1];
  const float* U     = (const float*)d_in[2];
  const float* gamma = (const float*)d_in[3];
  const float* beta  = (const float*)d_in[4];
  const float* rmean = (const float*)d_in[5];
  const float* rvar  = (const float*)d_in[6];
  float* out = (float*)d_out;

  const size_t wz_bytes = (size_t)MTOT * HDIM * sizeof(float);   // 65,536,000
  float* wzp = (float*)d_ws;
  u64*  xbuf = (u64*)((char*)d_ws + wz_bytes);                   // [2][16][512] u64

  hipMemsetAsync(xbuf, 0, (size_t)2 * NBATCH * HDIM * sizeof(u64), stream);

  dim3 g1(MTOT / 128, (HDIM * 2) / 128), b1(256);
  gemm_bn_f16_kernel<<<g1, b1, 0, stream>>>(x, W, gamma, beta, rmean, rvar, out, wzp);
  rnn_sync_kernel<<<dim3(128), dim3(512), 0, stream>>>(U, out, wzp, xbuf);
}